// Round 7
// baseline (272.561 us; speedup 1.0000x reference)
//
#include <hip/hip_runtime.h>
#include <hip/hip_bf16.h>
#include <climits>

#define B_ 2
#define V_ 4
#define H_ 120
#define W_ 160
#define C_ 96
#define NVOX 200000
#define GRID_ 128
#define NSTEPS 156
#define NRAYS (B_*V_*H_*W_)       // 153600
#define CHUNK 32                  // sorted-list entries per wave in chunk_reduce
#define NCHUNK ((NRAYS + CHUNK - 1) / CHUNK)  // 4800 max chunks
#define PARR 4                    // lanes cooperating per ray in march
#define MASK_W64 (B_ * GRID_ * GRID_ * GRID_ / 64)   // 65536 ull words = 512 KB

// ---- Kernel A: per-batch component-wise min via NEGATED atomicMax ----------
// sneg[b*3+k] = max(-coord) = -min(coord). Poison 0xAAAAAAAA (-1.43e9) loses
// to any -x for x in [0, 2^30], so sneg needs NO init memset.
__global__ void shift_kernel(const int* __restrict__ coords, int* __restrict__ sneg) {
    __shared__ int smax[B_ * 3];
    int t = threadIdx.x;
    if (t < B_ * 3) smax[t] = INT_MIN;
    __syncthreads();
    int i = blockIdx.x * blockDim.x + t;
    if (i < NVOX) {
        int b = coords[i * 4 + 0];
        atomicMax(&smax[b * 3 + 0], -coords[i * 4 + 1]);
        atomicMax(&smax[b * 3 + 1], -coords[i * 4 + 2]);
        atomicMax(&smax[b * 3 + 2], -coords[i * 4 + 3]);
    }
    __syncthreads();
    if (t < B_ * 3 && smax[t] != INT_MIN) atomicMax(&sneg[t], smax[t]);
}

// ------- Kernel B: occ id grid (last-dup wins) + 64-bit occupancy bitmask ---
// occ is NOT pre-initialized: reads are gated by the mask.
__global__ void occ_kernel(const int* __restrict__ coords,
                           const int* __restrict__ sneg,
                           int* __restrict__ occ,
                           unsigned long long* __restrict__ mask) {
    int i = blockIdx.x * blockDim.x + threadIdx.x;
    if (i >= NVOX) return;
    int b = coords[i * 4 + 0];
    int x = coords[i * 4 + 1] + sneg[b * 3 + 0];   // cx - min = cx + sneg
    int y = coords[i * 4 + 2] + sneg[b * 3 + 1];
    int z = coords[i * 4 + 3] + sneg[b * 3 + 2];
    int idx = ((b * GRID_ + z) * GRID_ + y) * GRID_ + x;
    atomicMax(&occ[idx], i);
    atomicOr(&mask[idx >> 6], 1ull << (idx & 63));
}

// -------- Kernel C: step-parallel march, 64-bit words + per-lane dedup ------
// Wave = 16 consecutive pixels x 4 step-blocks of 8 consecutive steps.
// Within a lane's 8 steps, a masked load is issued only when the 64-bit
// word index changes (~4 of 8), halving VMEM lane-slots.
__global__ void march_kernel(const float* __restrict__ vm,
                             const float* __restrict__ intr,
                             const int* __restrict__ sneg,
                             const unsigned long long* __restrict__ mask,
                             const int* __restrict__ occ,
                             int* __restrict__ tgt,
                             int* __restrict__ cnt) {
    int gt   = blockIdx.x * blockDim.x + threadIdx.x;
    int lane = threadIdx.x & 63;
    int p    = lane & 15;
    int sub  = lane >> 4;
    int r    = ((gt >> 6) << 4) + p;
    if (r >= NRAYS) return;
    int w = r % W_;
    int h = (r / W_) % H_;
    int v = (r / (W_ * H_)) % V_;
    int b = r / (W_ * H_ * V_);
    const float* M = vm + (size_t)(b * V_ + v) * 16;
    float fx = intr[0], fy = intr[1], cx = intr[2], cy = intr[3];
    float dx = ((float)w + 0.5f - cx) / fx;
    float dy = ((float)h + 0.5f - cy) / fy;
    float R00 = M[0], R01 = M[1], R02 = M[2];
    float R10 = M[4], R11 = M[5], R12 = M[6];
    float R20 = M[8], R21 = M[9], R22 = M[10];
    float t0 = M[3]  + (float)sneg[b * 3 + 0];
    float t1 = M[7]  + (float)sneg[b * 3 + 1];
    float t2 = M[11] + (float)sneg[b * 3 + 2];
    const int MISS = 0x7FFFFFFF;
    int beststep = MISS;
    for (int w0 = 0; w0 < NSTEPS; w0 += 32) {
        int lin[8]; bool ok[8];
#pragma unroll
        for (int j = 0; j < 8; ++j) {
            int st = w0 + sub * 8 + j;
            float t = 2.0f + 0.5f * (float)st;
            float px = dx * t, py = dy * t, pz = t;
            float pwx = R00 * px + R01 * py + R02 * pz + t0;
            float pwy = R10 * px + R11 * py + R12 * pz + t1;
            float pwz = R20 * px + R21 * py + R22 * pz + t2;
            int ix = (int)floorf(pwx);
            int iy = (int)floorf(pwy);
            int iz = (int)floorf(pwz);
            ok[j] = ((unsigned)ix < (unsigned)GRID_) &
                    ((unsigned)iy < (unsigned)GRID_) &
                    ((unsigned)iz < (unsigned)GRID_) & (st < NSTEPS);
            int cix = min(max(ix, 0), GRID_ - 1);
            int ciy = min(max(iy, 0), GRID_ - 1);
            int ciz = min(max(iz, 0), GRID_ - 1);
            lin[j] = ((b * GRID_ + ciz) * GRID_ + ciy) * GRID_ + cix;
        }
        unsigned long long u[8];
        bool same[8];
        same[0] = false;
#pragma unroll
        for (int j = 1; j < 8; ++j) same[j] = ((lin[j] >> 6) == (lin[j - 1] >> 6));
#pragma unroll
        for (int j = 0; j < 8; ++j)
            if (!same[j]) u[j] = mask[lin[j] >> 6];   // independent masked loads
#pragma unroll
        for (int j = 1; j < 8; ++j)
            if (same[j]) u[j] = u[j - 1];             // propagate after waitcnt
        int local = MISS;
#pragma unroll
        for (int j = 0; j < 8; ++j) {
            int st = w0 + sub * 8 + j;
            if (ok[j] && ((u[j] >> (lin[j] & 63)) & 1ull)) local = min(local, st);
        }
        local = min(local, __shfl_xor(local, 16));
        local = min(local, __shfl_xor(local, 32));
        if (local != MISS) { beststep = local; break; }
    }
    if (sub == 0) {
        int res = -1;
        if (beststep != MISS) {
            float t = 2.0f + 0.5f * (float)beststep;
            float px = dx * t, py = dy * t, pz = t;
            float pwx = R00 * px + R01 * py + R02 * pz + t0;
            float pwy = R10 * px + R11 * py + R12 * pz + t1;
            float pwz = R20 * px + R21 * py + R22 * pz + t2;
            int ix = (int)floorf(pwx);
            int iy = (int)floorf(pwy);
            int iz = (int)floorf(pwz);
            res = occ[((b * GRID_ + iz) * GRID_ + iy) * GRID_ + ix];
        }
        tgt[r] = res;
        if (res >= 0) atomicAdd(&cnt[res], 1);
    }
}

// ---- Kernel D: atomic segment allocator (replaces scan1/2/3) ---------------
// Bucket order is irrelevant — only per-voxel contiguity matters. Each block
// aggregates its 256 counts (wave shfl-scan + LDS) and grabs one global
// atomicAdd. Also zeroes the 'out' rows of chunk-crossing segments so
// chunk_reduce can atomically accumulate into them (no 77 MB d_out memset).
__global__ void alloc_kernel(const int* __restrict__ cnt,
                             int* __restrict__ gtotal,
                             int* __restrict__ segstart,
                             int* __restrict__ cursor,
                             float* __restrict__ out) {
    __shared__ int wtot[4];
    __shared__ int bbase;
    int tid  = threadIdx.x;
    int lane = tid & 63;
    int wid  = tid >> 6;
    int i = blockIdx.x * 256 + tid;
    int c = (i < NVOX) ? cnt[i] : 0;
    // wave inclusive scan
    int x = c;
#pragma unroll
    for (int d = 1; d < 64; d <<= 1) {
        int y = __shfl_up(x, d);
        if (lane >= d) x += y;
    }
    if (lane == 63) wtot[wid] = x;
    __syncthreads();
    if (tid == 0) {
        int s0 = wtot[0], s1 = wtot[1], s2 = wtot[2], s3 = wtot[3];
        int tot = s0 + s1 + s2 + s3;
        int base = atomicAdd(gtotal, tot);
        wtot[0] = base;
        wtot[1] = base + s0;
        wtot[2] = base + s0 + s1;
        wtot[3] = base + s0 + s1 + s2;
        (void)bbase;
    }
    __syncthreads();
    if (i >= NVOX) return;
    int s = wtot[wid] + (x - c);          // exclusive position
    segstart[i] = s;
    cursor[i]   = s;
    if (c > 0) {
        int e = s + c;
        if ((s / CHUNK) != ((e - 1) / CHUNK)) {   // crossing: pre-zero out row
            float4* o = (float4*)(out + (size_t)i * C_);
#pragma unroll
            for (int q = 0; q < C_ / 4; ++q) o[q] = make_float4(0.f, 0.f, 0.f, 0.f);
        }
    }
}

// ---------------- Kernel F: bucket rays by target (counting sort) -----------
__global__ void order_kernel(const int* __restrict__ tgt,
                             int* __restrict__ cursor, int2* __restrict__ sorted_rt) {
    int r = blockIdx.x * blockDim.x + threadIdx.x;
    if (r >= NRAYS) return;
    int t = tgt[r];
    if (t < 0) return;
    int pos = atomicAdd(&cursor[t], 1);
    sorted_rt[pos] = make_int2(r, t);
}

// ---------------- run flush: middle runs need no cnt/segstart ---------------
__device__ __forceinline__ void flush_run2(int t, int ks, int ke, int n,
                                           float ax, float ay, int lane,
                                           const int* __restrict__ segstart,
                                           const int* __restrict__ cnt,
                                           float* __restrict__ out,
                                           float* __restrict__ cnt_out) {
    int c;
    bool complete;
    if (ks > 0 && ke < n) {
        c = ke - ks;
        complete = true;
    } else {
        c = cnt[t];
        int s = segstart[t];
        int e = s + c;
        complete = (s / CHUNK) == ((e - 1) / CHUNK);
    }
    if (complete) {
        float denom = (float)c + 0.0001f;
        if (lane < 48) {
            float2 wv; wv.x = ax / denom; wv.y = ay / denom;
            ((float2*)(out + (size_t)t * C_))[lane] = wv;
        }
        if (lane == 0) cnt_out[t] = (float)c;
    } else if (lane < 48) {
        unsafeAtomicAdd(out + (size_t)t * C_ + 2 * lane,     ax);
        unsafeAtomicAdd(out + (size_t)t * C_ + 2 * lane + 1, ay);
    }
}

// ---------------- Kernel G: load-balanced chunked segmented reduce ----------
__global__ void chunk_reduce_kernel(const float* __restrict__ feats,
                                    const int2* __restrict__ sorted_rt,
                                    const int* __restrict__ segstart,
                                    const int* __restrict__ cnt,
                                    const int* __restrict__ total_p,
                                    float* __restrict__ out,
                                    float* __restrict__ cnt_out) {
    int wave = (blockIdx.x * blockDim.x + threadIdx.x) >> 6;
    int lane = threadIdx.x & 63;
    int total = total_p[0];
    int a = wave * CHUNK;
    if (a >= total) return;
    int n = min(CHUNK, total - a);
    int myr = 0, myt = 0;
    if (lane < n) { int2 e = sorted_rt[a + lane]; myr = e.x; myt = e.y; }
    float ax = 0.0f, ay = 0.0f;
    int cur = -1, run_start = 0;
    for (int k0 = 0; k0 < n; k0 += 4) {
        float2 vbuf[4]; int tt[4];
#pragma unroll
        for (int j = 0; j < 4; ++j) {
            int k = k0 + j;
            int rr = __shfl(myr, k);
            tt[j]  = __shfl(myt, k);
            vbuf[j] = make_float2(0.0f, 0.0f);
            if (k < n && lane < 48)
                vbuf[j] = ((const float2*)(feats + (size_t)rr * C_))[lane];
        }
#pragma unroll
        for (int j = 0; j < 4; ++j) {
            int k = k0 + j;
            if (k >= n) break;
            if (tt[j] != cur) {
                if (cur >= 0)
                    flush_run2(cur, run_start, k, n, ax, ay, lane, segstart, cnt, out, cnt_out);
                cur = tt[j]; run_start = k; ax = 0.0f; ay = 0.0f;
            }
            ax += vbuf[j].x; ay += vbuf[j].y;
        }
    }
    flush_run2(cur, run_start, n, n, ax, ay, lane, segstart, cnt, out, cnt_out);
}

// ---- Kernel H: finalize — divide crossing, write empty rows + cnt_out ------
__global__ void finalize_kernel(const int* __restrict__ segstart,
                                const int* __restrict__ cnt,
                                float* __restrict__ out,
                                float* __restrict__ cnt_out) {
    int vox  = (blockIdx.x * blockDim.x + threadIdx.x) >> 6;
    int lane = threadIdx.x & 63;
    if (vox >= NVOX) return;
    int c = cnt[vox];
    if (c == 0) {
        if (lane < 48) {
            float2 z; z.x = 0.0f; z.y = 0.0f;
            ((float2*)(out + (size_t)vox * C_))[lane] = z;
        }
        if (lane == 0) cnt_out[vox] = 0.0f;
        return;
    }
    int s = segstart[vox], e = s + c;
    if (s / CHUNK == (e - 1) / CHUNK) return;   // complete: chunk kernel wrote it
    float denom = (float)c + 0.0001f;
    if (lane < 48) {
        float2* o = (float2*)(out + (size_t)vox * C_);
        float2 x = o[lane];
        x.x /= denom; x.y /= denom;
        o[lane] = x;
    }
    if (lane == 0) cnt_out[vox] = (float)c;
}

extern "C" void kernel_launch(void* const* d_in, const int* in_sizes, int n_in,
                              void* d_out, int out_size, void* d_ws, size_t ws_size,
                              hipStream_t stream) {
    const float* feats  = (const float*)d_in[0];
    const int*   coords = (const int*)d_in[1];
    const float* vm     = (const float*)d_in[2];
    const float* intr   = (const float*)d_in[3];

    float* out     = (float*)d_out;                  // NVOX*C_ floats
    float* cnt_out = out + (size_t)NVOX * C_;        // NVOX floats

    char* ws = (char*)d_ws;
    int* sneg = (int*)ws;                                    // 256 B (no init needed)
    // --- contiguous zero region: cnt | mask | gtotal ---
    int*                cnt    = (int*)(ws + 256);           // 800,000 B
    unsigned long long* mask   = (unsigned long long*)(ws + 800256);  // 524,288 B
    int*                gtotal = (int*)(ws + 1324544);       // 4 B (zero region ends 1324608)
    // --- uninitialized scratch ---
    int*  tgt       = (int*)(ws + 1324608);                  // 614,400 B
    int*  segstart  = (int*)(ws + 1939008);                  // 800,000 B
    int*  cursor    = (int*)(ws + 2739008);                  // 800,000 B
    int2* sorted_rt = (int2*)(ws + 3539008);                 // 1,228,800 B
    int*  occ       = (int*)(ws + 4767808);                  // 33,554,432 B (mask-gated)

    hipMemsetAsync(ws + 256, 0, 1324352, stream);            // cnt+mask+gtotal in ONE fill

    shift_kernel<<<(NVOX + 255) / 256, 256, 0, stream>>>(coords, sneg);
    occ_kernel<<<(NVOX + 255) / 256, 256, 0, stream>>>(coords, sneg, occ, mask);
    march_kernel<<<(NRAYS * PARR + 255) / 256, 256, 0, stream>>>(vm, intr, sneg, mask, occ, tgt, cnt);
    alloc_kernel<<<(NVOX + 255) / 256, 256, 0, stream>>>(cnt, gtotal, segstart, cursor, out);
    order_kernel<<<(NRAYS + 255) / 256, 256, 0, stream>>>(tgt, cursor, sorted_rt);
    chunk_reduce_kernel<<<(NCHUNK * 64 + 255) / 256, 256, 0, stream>>>(
        feats, sorted_rt, segstart, cnt, gtotal, out, cnt_out);
    finalize_kernel<<<((size_t)NVOX * 64 + 255) / 256, 256, 0, stream>>>(
        segstart, cnt, out, cnt_out);
}